// Round 6
// baseline (127.963 us; speedup 1.0000x reference)
//
#include <hip/hip_runtime.h>
#include <math.h>

// Problem constants (from reference)
#define N_NODES 8192        // N_IN == N_OUT == 8192
#define C_OUT 32
#define GDIM  192           // 64 cells * 3 input channels
constexpr float INV_RADIUS   = 1.0f / 0.1125f;   // RADIUS = 1.5*6*0.025/2
constexpr float EPS          = 1e-12f;
constexpr float FOUR_OVER_PI = 1.27323954473516f;

__device__ __forceinline__ float sgnf(float v) {
    return (v > 0.f) ? 1.f : ((v < 0.f) ? -1.f : 0.f);
}

// Workspace layout (d_ws):
//   pv      : 8192 * 8 floats  (pos.xyz,0, vel.xyz,0)   = 262144 B  @ 0
//   row_off : 8193 ints                                  =  32772 B  @ 262144
//   G       : 8192 * 192 floats                          = 6291456 B @ 294928 (16B aligned)
#define PV_OFF   0
#define ROFF_OFF 262144
#define G_OFF    294928

// Kernel 1: CSR row offsets from sorted dst + pack pos0/vel into float4 pairs.
__global__ __launch_bounds__(256) void prep_kernel(
    const float* __restrict__ pos0,
    const float* __restrict__ vel,
    const int*   __restrict__ dst,
    const float* __restrict__ mask,
    int E,
    int*   __restrict__ row_off,
    float* __restrict__ pv)
{
    int n = blockIdx.x * blockDim.x + threadIdx.x;
    if (n < N_NODES) {
        float4 p = make_float4(pos0[3*n+0], pos0[3*n+1], pos0[3*n+2], 0.f);
        float4 v = make_float4(vel [3*n+0], vel [3*n+1], vel [3*n+2], 0.f);
        ((float4*)pv)[2*n+0] = p;
        ((float4*)pv)[2*n+1] = v;
    }
    if (n > N_NODES) return;
    int lo = 0, hi = E;
    while (lo < hi) { int mid = (lo + hi) >> 1; if (mask[mid] != 0.f) lo = mid + 1; else hi = mid; }
    int Ereal = lo;
    if (n == N_NODES) { row_off[n] = Ereal; return; }
    lo = 0; hi = Ereal;
    while (lo < hi) { int mid = (lo + hi) >> 1; if (dst[mid] < n) lo = mid + 1; else hi = mid; }
    row_off[n] = lo;
}

// Kernel 2 (ABLATION TEMPLATE): one wave per destination node.
// V=0: full.  V=1: no DS atomics (geometry live via asm sink).
// V=2: no geometry (synthetic corners, keeps gathers+DS).  V=3: gathers only.
// V!=0 variants still write (garbage) rows into G; V0 runs LAST and fully
// rewrites every row, so the result is unchanged and deterministic.
template<int V>
__global__ __launch_bounds__(256) void scatter_kernel(
    const float* __restrict__ pv,
    const float* __restrict__ pos1,
    const int*   __restrict__ src,
    const int*   __restrict__ row_off,
    float* __restrict__ G)
{
    __shared__ float Gl[4][GDIM];                   // 3 KiB
    int t = threadIdx.x, wave = t >> 6, lane = t & 63;
    int n = blockIdx.x * 4 + wave;

    #pragma unroll
    for (int i = lane; i < GDIM; i += 64) Gl[wave][i] = 0.f;

    float px = pos1[3*n+0], py = pos1[3*n+1], pz = pos1[3*n+2];
    int e0 = row_off[n], e1 = row_off[n+1];

    for (int e = e0 + lane; e < e1; e += 64) {
        int s = src[e];
        float4 p = ((const float4*)pv)[2*s+0];
        float4 v = ((const float4*)pv)[2*s+1];

        if constexpr (V == 3) {       // gathers only
            asm volatile("" :: "v"(p.x), "v"(p.y), "v"(p.z),
                              "v"(v.x), "v"(v.y), "v"(v.z));
            continue;
        }

        float rx = (p.x - px) * INV_RADIUS;
        float ry = (p.y - py) * INV_RADIUS;
        float rz = (p.z - pz) * INV_RADIUS;
        float r2 = rx*rx + ry*ry + rz*rz;
        if (r2 >= 1.f) continue;
        float om  = 1.f - r2;
        float win = om*om*om;

        if constexpr (V == 2) {       // no geometry: synthetic corner pattern
            int base = s & 63;
            float w = win * 0.125f;
            #pragma unroll
            for (int k = 0; k < 8; ++k) {
                int idx = (base + k*7) & 63;
                int a   = idx * 3;
                unsafeAtomicAdd(&Gl[wave][a + 0], w * v.x);
                unsafeAtomicAdd(&Gl[wave][a + 1], w * v.y);
                unsafeAtomicAdd(&Gl[wave][a + 2], w * v.z);
            }
            continue;
        }

        // ball -> cube (volume preserving)
        float x = rx, y = ry, z = rz;
        float norm = sqrtf(r2 + EPS);
        float cx, cy, cz;
        if (r2 < 1e-12f) {
            cx = 0.f; cy = 0.f; cz = 0.f;
        } else if (1.25f*z*z > x*x + y*y) {
            float s_top = sqrtf(3.f*norm / (norm + fabsf(z) + EPS));
            cx = x * s_top;
            cy = y * s_top;
            cz = sgnf(z) * norm;
        } else {
            float s_side = norm * rsqrtf(x*x + y*y + EPS);
            cx = x * s_side;
            cy = y * s_side;
            cz = 1.5f * z;
        }

        float nxy = sqrtf(cx*cx + cy*cy + EPS);
        float ux, uy;
        if (cx*cx >= cy*cy) {
            float xs = (fabsf(cx) > EPS) ? cx : 1.f;
            float sc = sgnf(cx);
            ux = sc * nxy;
            uy = sc * nxy * FOUR_OVER_PI * atanf(cy / xs);
        } else {
            float ys = (fabsf(cy) > EPS) ? cy : 1.f;
            float sc = sgnf(cy);
            ux = sc * nxy * FOUR_OVER_PI * atanf(cx / ys);
            uy = sc * nxy;
        }
        if (cx*cx + cy*cy < 1e-12f) { ux = 0.f; uy = 0.f; }

        float gx = fminf(fmaxf((ux + 1.f) * 1.5f, 0.f), 3.f);
        float gy = fminf(fmaxf((uy + 1.f) * 1.5f, 0.f), 3.f);
        float gz = fminf(fmaxf((cz + 1.f) * 1.5f, 0.f), 3.f);
        int ix = min((int)floorf(gx), 2);
        int iy = min((int)floorf(gy), 2);
        int iz = min((int)floorf(gz), 2);
        float fx = gx - (float)ix;
        float fy = gy - (float)iy;
        float fz = gz - (float)iz;

        float ofx = 1.f - fx, ofy = 1.f - fy, ofz = 1.f - fz;
        int base = (iz * 4 + iy) * 4 + ix;

        if constexpr (V == 1) {       // no DS: keep geometry live
            asm volatile("" :: "v"(fx), "v"(fy), "v"(fz), "v"(win),
                              "v"(v.x), "v"(v.y), "v"(v.z), "v"((float)base));
            continue;
        }

        int rot = lane & 7;
        #pragma unroll
        for (int k = 0; k < 8; ++k) {
            int c  = k ^ rot;
            float wz = (c & 4) ? fz : ofz;
            float wy = (c & 2) ? fy : ofy;
            float wx = (c & 1) ? fx : ofx;
            float w  = wz * wy * wx * win;
            int idx  = base + ((c & 4) << 2) + ((c & 2) << 1) + (c & 1);
            int a    = idx * 3;
            unsafeAtomicAdd(&Gl[wave][a + 0], w * v.x);
            unsafeAtomicAdd(&Gl[wave][a + 1], w * v.y);
            unsafeAtomicAdd(&Gl[wave][a + 2], w * v.z);
        }
    }

    if (lane < GDIM/4) {
        float4 r = ((float4*)Gl[wave])[lane];
        ((float4*)(G + (size_t)n * GDIM))[lane] = r;
    }
}

// Kernel 3: out[n][o] = b[o] + sum_j G[n][j] * W[j][o]; 8 nodes per 256-thr block.
__global__ __launch_bounds__(256) void gemm_kernel(
    const float* __restrict__ G,
    const float* __restrict__ W,
    const float* __restrict__ b,
    float* __restrict__ out)
{
    __shared__ float Wl[GDIM * C_OUT];   // 24 KiB
    __shared__ float Gls[8 * GDIM];      //  6 KiB
    __shared__ float bl[C_OUT];
    int t = threadIdx.x;
    for (int i = t; i < GDIM * C_OUT / 4; i += 256)
        ((float4*)Wl)[i] = ((const float4*)W)[i];
    if (t < C_OUT) bl[t] = b[t];
    const float4* Gg = (const float4*)(G + (size_t)blockIdx.x * 8 * GDIM);
    for (int i = t; i < 8 * GDIM / 4; i += 256)
        ((float4*)Gls)[i] = Gg[i];
    __syncthreads();

    int node = t >> 5, o = t & 31;
    const float* g = Gls + node * GDIM;
    float acc = bl[o];
    #pragma unroll 8
    for (int j = 0; j < GDIM; ++j)
        acc += g[j] * Wl[j * C_OUT + o];
    out[(blockIdx.x * 8 + node) * C_OUT + o] = acc;
}

extern "C" void kernel_launch(void* const* d_in, const int* in_sizes, int n_in,
                              void* d_out, int out_size, void* d_ws, size_t ws_size,
                              hipStream_t stream)
{
    const float* vel  = (const float*)d_in[0];
    const float* pos0 = (const float*)d_in[1];
    const float* pos1 = (const float*)d_in[2];
    const float* W    = (const float*)d_in[3];
    const float* b    = (const float*)d_in[4];
    const int*   src  = (const int*)d_in[5];
    const int*   dst  = (const int*)d_in[6];
    const float* mask = (const float*)d_in[7];
    int E = in_sizes[5];

    char* ws = (char*)d_ws;
    float* pv      = (float*)(ws + PV_OFF);
    int*   row_off = (int*)  (ws + ROFF_OFF);
    float* G       = (float*)(ws + G_OFF);

    prep_kernel<<<(N_NODES + 256) / 256, 256, 0, stream>>>(pos0, vel, dst, mask, E, row_off, pv);

    // --- ablation dispatches (results overwritten by V0 below) ---
    scatter_kernel<3><<<N_NODES / 4, 256, 0, stream>>>(pv, pos1, src, row_off, G);
    scatter_kernel<2><<<N_NODES / 4, 256, 0, stream>>>(pv, pos1, src, row_off, G);
    scatter_kernel<1><<<N_NODES / 4, 256, 0, stream>>>(pv, pos1, src, row_off, G);
    // --- the real one: fully rewrites every G row ---
    scatter_kernel<0><<<N_NODES / 4, 256, 0, stream>>>(pv, pos1, src, row_off, G);

    gemm_kernel<<<N_NODES / 8, 256, 0, stream>>>(G, W, b, (float*)d_out);
}

// Round 7
// 68.870 us; speedup vs baseline: 1.8581x; 1.8581x over previous
//
#include <hip/hip_runtime.h>
#include <math.h>

// Problem constants (from reference)
#define N_NODES 8192        // N_IN == N_OUT == 8192
#define C_OUT 32
#define GDIM  192           // 64 cells * 3 input channels
#define NB    16            // nodes per scatter block
constexpr float INV_RADIUS   = 1.0f / 0.1125f;   // RADIUS = 1.5*6*0.025/2
constexpr float EPS          = 1e-12f;
constexpr float FOUR_OVER_PI = 1.27323954473516f;

// Fast hardware transcendentals (no IEEE-div sequence, no ocml calls).
__device__ __forceinline__ float frcp(float x)  { float r; asm("v_rcp_f32 %0, %1"  : "=v"(r) : "v"(x)); return r; }
__device__ __forceinline__ float frsq(float x)  { float r; asm("v_rsq_f32 %0, %1"  : "=v"(r) : "v"(x)); return r; }
__device__ __forceinline__ float fsqrt_(float x){ float r; asm("v_sqrt_f32 %0, %1" : "=v"(r) : "v"(x)); return r; }

__device__ __forceinline__ float sgnf(float v) {
    return (v > 0.f) ? 1.f : ((v < 0.f) ? -1.f : 0.f);
}

// minimax odd polynomial for atan(q), |q| <= 1, max err ~1e-5
__device__ __forceinline__ float atan01(float q) {
    float t = q * q;
    float p = fmaf(t, -0.01172120f, 0.05265332f);
    p = fmaf(t, p, -0.11643287f);
    p = fmaf(t, p,  0.19354346f);
    p = fmaf(t, p, -0.33262347f);
    p = fmaf(t, p,  0.99997726f);
    return q * p;
}

// Workspace layout (d_ws):
//   pv      : 8192 * 8 floats  (pos.xyz,0, vel.xyz,0)   = 262144 B  @ 0
//   row_off : 8193 ints                                  =  32772 B  @ 262144
//   G       : 8192 * 192 floats                          = 6291456 B @ 294928 (16B aligned)
#define PV_OFF   0
#define ROFF_OFF 262144
#define G_OFF    294928

// Kernel 1: CSR row offsets from sorted dst + pack pos0/vel into float4 pairs.
__global__ __launch_bounds__(256) void prep_kernel(
    const float* __restrict__ pos0,
    const float* __restrict__ vel,
    const int*   __restrict__ dst,
    const float* __restrict__ mask,
    int E,
    int*   __restrict__ row_off,
    float* __restrict__ pv)
{
    int n = blockIdx.x * blockDim.x + threadIdx.x;
    if (n < N_NODES) {
        float4 p = make_float4(pos0[3*n+0], pos0[3*n+1], pos0[3*n+2], 0.f);
        float4 v = make_float4(vel [3*n+0], vel [3*n+1], vel [3*n+2], 0.f);
        ((float4*)pv)[2*n+0] = p;
        ((float4*)pv)[2*n+1] = v;
    }
    if (n > N_NODES) return;
    int lo = 0, hi = E;
    while (lo < hi) { int mid = (lo + hi) >> 1; if (mask[mid] != 0.f) lo = mid + 1; else hi = mid; }
    int Ereal = lo;
    if (n == N_NODES) { row_off[n] = Ereal; return; }
    lo = 0; hi = Ereal;
    while (lo < hi) { int mid = (lo + hi) >> 1; if (dst[mid] < n) lo = mid + 1; else hi = mid; }
    row_off[n] = lo;
}

// Kernel 2: EDGE-PARALLEL scatter. Each 256-thread block owns 16 consecutive
// nodes; threads stride the block's contiguous CSR edge range (~690 edges,
// ~3/thread -> real loop, ILP). LDS rows + rotated ds_add accumulation.
__global__ __launch_bounds__(256) void scatter_kernel(
    const float* __restrict__ pv,
    const float* __restrict__ pos1,
    const int*   __restrict__ src,
    const int*   __restrict__ dst,
    const int*   __restrict__ row_off,
    float* __restrict__ G)
{
    __shared__ float Gl[NB * GDIM];     // 12 KiB
    __shared__ float posl[NB * 4];

    int t = threadIdx.x;
    int n0 = blockIdx.x * NB;

    if (t < NB) {
        posl[t*4+0] = pos1[(n0+t)*3+0];
        posl[t*4+1] = pos1[(n0+t)*3+1];
        posl[t*4+2] = pos1[(n0+t)*3+2];
    }
    #pragma unroll
    for (int i = t; i < NB * GDIM; i += 256) Gl[i] = 0.f;
    __syncthreads();

    int e0 = row_off[n0], e1 = row_off[n0 + NB];
    int rot = t & 7;

    for (int e = e0 + t; e < e1; e += 256) {
        int s = src[e];
        int d = dst[e] - n0;
        float4 p = ((const float4*)pv)[2*s+0];
        float4 v = ((const float4*)pv)[2*s+1];
        float px = posl[d*4+0], py = posl[d*4+1], pz = posl[d*4+2];

        float rx = (p.x - px) * INV_RADIUS;
        float ry = (p.y - py) * INV_RADIUS;
        float rz = (p.z - pz) * INV_RADIUS;
        float r2 = rx*rx + ry*ry + rz*rz;
        if (r2 >= 1.f) continue;
        float om  = 1.f - r2;
        float win = om * om * om;

        // ball -> cube (volume preserving), branchless
        float x = rx, y = ry, z = rz;
        float ax2y2 = x*x + y*y;
        float norm  = fsqrt_(r2 + EPS);
        bool  top   = 1.25f * z * z > ax2y2;
        float s_top  = fsqrt_(3.f * norm * frcp(norm + fabsf(z) + EPS));
        float s_side = norm * frsq(ax2y2 + EPS);
        float sel = top ? s_top : s_side;
        float cx = x * sel;
        float cy = y * sel;
        float cz = top ? sgnf(z) * norm : 1.5f * z;
        bool zero = r2 < 1e-12f;
        cx = zero ? 0.f : cx;  cy = zero ? 0.f : cy;  cz = zero ? 0.f : cz;

        float cx2 = cx*cx, cy2 = cy*cy;
        float nxy = fsqrt_(cx2 + cy2 + EPS);
        bool  c1  = cx2 >= cy2;
        float xs  = (fabsf(cx) > EPS) ? cx : 1.f;
        float ys  = (fabsf(cy) > EPS) ? cy : 1.f;
        float num = c1 ? cy : cx;
        float den = c1 ? xs : ys;
        float at  = atan01(num * frcp(den)) * FOUR_OVER_PI * nxy;
        float scx = sgnf(cx), scy = sgnf(cy);
        float ux = c1 ? scx * nxy : scy * at;
        float uy = c1 ? scx * at  : scy * nxy;
        bool zxy = (cx2 + cy2) < 1e-12f;
        ux = zxy ? 0.f : ux;  uy = zxy ? 0.f : uy;

        // grid coords in [0,3], corner index + fractions
        float gx = fminf(fmaxf((ux + 1.f) * 1.5f, 0.f), 3.f);
        float gy = fminf(fmaxf((uy + 1.f) * 1.5f, 0.f), 3.f);
        float gz = fminf(fmaxf((cz + 1.f) * 1.5f, 0.f), 3.f);
        int ix = min((int)gx, 2);
        int iy = min((int)gy, 2);
        int iz = min((int)gz, 2);
        float fx = gx - (float)ix;
        float fy = gy - (float)iy;
        float fz = gz - (float)iz;

        float ofx = 1.f - fx, ofy = 1.f - fy, ofz = 1.f - fz;
        int base = (iz * 4 + iy) * 4 + ix;
        float* Gd = Gl + d * GDIM;

        // Lane-rotated corner order: colliding lanes hit different addresses
        // on each DS instruction.
        #pragma unroll
        for (int k = 0; k < 8; ++k) {
            int c  = k ^ rot;
            float wz = (c & 4) ? fz : ofz;
            float wy = (c & 2) ? fy : ofy;
            float wx = (c & 1) ? fx : ofx;
            float w  = wz * wy * wx * win;
            int idx  = base + ((c & 4) << 2) + ((c & 2) << 1) + (c & 1);
            int a    = idx * 3;
            unsafeAtomicAdd(&Gd[a + 0], w * v.x);
            unsafeAtomicAdd(&Gd[a + 1], w * v.y);
            unsafeAtomicAdd(&Gd[a + 2], w * v.z);
        }
    }
    __syncthreads();

    // coalesced block writeout: Gl is exactly rows n0..n0+15 of G
    const float4* Gs = (const float4*)Gl;
    float4* Gg = (float4*)(G + (size_t)n0 * GDIM);
    #pragma unroll
    for (int i = t; i < NB * GDIM / 4; i += 256) Gg[i] = Gs[i];
}

// Kernel 3: out[n][o] = b[o] + sum_j G[n][j] * W[j][o]; 8 nodes per 256-thr block.
__global__ __launch_bounds__(256) void gemm_kernel(
    const float* __restrict__ G,
    const float* __restrict__ W,
    const float* __restrict__ b,
    float* __restrict__ out)
{
    __shared__ float Wl[GDIM * C_OUT];   // 24 KiB
    __shared__ float Gls[8 * GDIM];      //  6 KiB
    __shared__ float bl[C_OUT];
    int t = threadIdx.x;
    for (int i = t; i < GDIM * C_OUT / 4; i += 256)
        ((float4*)Wl)[i] = ((const float4*)W)[i];
    if (t < C_OUT) bl[t] = b[t];
    const float4* Gg = (const float4*)(G + (size_t)blockIdx.x * 8 * GDIM);
    for (int i = t; i < 8 * GDIM / 4; i += 256)
        ((float4*)Gls)[i] = Gg[i];
    __syncthreads();

    int node = t >> 5, o = t & 31;
    const float* g = Gls + node * GDIM;
    float acc = bl[o];
    #pragma unroll 8
    for (int j = 0; j < GDIM; ++j)
        acc += g[j] * Wl[j * C_OUT + o];
    out[(blockIdx.x * 8 + node) * C_OUT + o] = acc;
}

extern "C" void kernel_launch(void* const* d_in, const int* in_sizes, int n_in,
                              void* d_out, int out_size, void* d_ws, size_t ws_size,
                              hipStream_t stream)
{
    const float* vel  = (const float*)d_in[0];
    const float* pos0 = (const float*)d_in[1];
    const float* pos1 = (const float*)d_in[2];
    const float* W    = (const float*)d_in[3];
    const float* b    = (const float*)d_in[4];
    const int*   src  = (const int*)d_in[5];
    const int*   dst  = (const int*)d_in[6];
    const float* mask = (const float*)d_in[7];
    int E = in_sizes[5];

    char* ws = (char*)d_ws;
    float* pv      = (float*)(ws + PV_OFF);
    int*   row_off = (int*)  (ws + ROFF_OFF);
    float* G       = (float*)(ws + G_OFF);

    prep_kernel<<<(N_NODES + 256) / 256, 256, 0, stream>>>(pos0, vel, dst, mask, E, row_off, pv);
    scatter_kernel<<<N_NODES / NB, 256, 0, stream>>>(pv, pos1, src, dst, row_off, G);
    gemm_kernel<<<N_NODES / 8, 256, 0, stream>>>(G, W, b, (float*)d_out);
}